// Round 1
// baseline (946.062 us; speedup 1.0000x reference)
//
#include <hip/hip_runtime.h>

#define EPS 1e-5f
typedef long long ll;
typedef unsigned int uint;

// cnt[] is padded to one counter per 128B cache line to kill same-line
// serialization of memory-side atomic RMWs (was 32 counters/line -> ~427
// atomics/line; now 1 counter/line -> contention = bucket degree only).
#define CNT_STRIDE 32

__device__ __forceinline__ uint bf_round(float x) {
    uint u = __float_as_uint(x);
    return (u + 0x7FFFu + ((u >> 16) & 1u)) >> 16;
}
__device__ __forceinline__ uint pack2(float a, float b) {
    return bf_round(a) | (bf_round(b) << 16);
}
__device__ __forceinline__ float unpack_lo(uint u) { return __uint_as_float(u << 16); }
__device__ __forceinline__ float unpack_hi(uint u) { return __uint_as_float(u & 0xFFFF0000u); }

// ---- fused prep: blocks [0,cb) do count+rank, blocks [cb,cb+tb) do f32->bf16 ----
__global__ __launch_bounds__(256) void prep_kernel(
    const int* __restrict__ rows, const int* __restrict__ cols,
    int* __restrict__ cnt, int* __restrict__ rank_r, int* __restrict__ rank_c,
    int ne, int nu, int cb,
    const float* __restrict__ ue, const float* __restrict__ ie,
    uint4* __restrict__ bfout, int nuT, int totT)
{
    int b = blockIdx.x;
    if (b < cb) {
        int e = b * 256 + threadIdx.x;
        if (e < ne) {
            rank_r[e] = atomicAdd(&cnt[rows[e] * CNT_STRIDE], 1);
            rank_c[e] = atomicAdd(&cnt[(nu + cols[e]) * CNT_STRIDE], 1);
        }
    } else {
        int t = (b - cb) * 256 + threadIdx.x;
        if (t < totT) {
            const float4* src = (t < nuT) ? (const float4*)(ue + (ll)t * 8)
                                          : (const float4*)(ie + (ll)(t - nuT) * 8);
            float4 f0 = src[0], f1 = src[1];
            uint4 q;
            q.x = pack2(f0.x, f0.y); q.y = pack2(f0.z, f0.w);
            q.z = pack2(f1.x, f1.y); q.w = pack2(f1.z, f1.w);
            bfout[t] = q;
        }
    }
}

// ============ scans ============
__global__ __launch_bounds__(256) void scanA(
    const int* __restrict__ cnt, int* __restrict__ rowptr,
    int* __restrict__ blockpart, int n)
{
    __shared__ int sm[256];
    int t = threadIdx.x;
    int base = blockIdx.x * 1024 + t * 4;
    int v[4]; int s = 0;
#pragma unroll
    for (int k = 0; k < 4; k++) {
        int i = base + k;
        v[k] = (i < n) ? cnt[i * CNT_STRIDE] : 0;
        s += v[k];
    }
    sm[t] = s; __syncthreads();
    for (int off = 1; off < 256; off <<= 1) {
        int a = (t >= off) ? sm[t - off] : 0;
        __syncthreads();
        sm[t] += a;
        __syncthreads();
    }
    int excl = sm[t] - s;
    if (t == 255) blockpart[blockIdx.x] = sm[255];
    int run = excl;
#pragma unroll
    for (int k = 0; k < 4; k++) {
        int i = base + k;
        if (i < n) rowptr[i] = run;
        run += v[k];
    }
}

__global__ __launch_bounds__(512) void scanB(int* __restrict__ blockpart, int nb)
{
    __shared__ int sm[512];
    int t = threadIdx.x;
    int v = (t < nb) ? blockpart[t] : 0;
    sm[t] = v; __syncthreads();
    for (int off = 1; off < 512; off <<= 1) {
        int a = (t >= off) ? sm[t - off] : 0;
        __syncthreads();
        sm[t] += a;
        __syncthreads();
    }
    if (t < nb) blockpart[t] = sm[t] - v;
}

__global__ __launch_bounds__(256) void scanC(
    int* __restrict__ rowptr, const int* __restrict__ blockpart, int n, int total)
{
    int i = blockIdx.x * 256 + threadIdx.x;
    if (i < n) rowptr[i] += blockpart[i >> 10];
    if (i == 0) rowptr[n] = total;
}

// atomic-free fill: slot = rowptr[bucket] + precomputed rank.
__global__ __launch_bounds__(256) void fill_kernel(
    const int* __restrict__ rows, const int* __restrict__ cols,
    const float* __restrict__ vals,
    const int* __restrict__ rowptr,
    const int* __restrict__ rank_r, const int* __restrict__ rank_c,
    int2* __restrict__ csr, int ne, int nu)
{
    int e = blockIdx.x * 256 + threadIdx.x;
    if (e >= ne) return;
    int r = rows[e], c = cols[e];
    int vb = __float_as_int(vals[e]);
    int p = rowptr[r] + rank_r[e];
    csr[p] = make_int2(c, vb);
    int q = rowptr[nu + c] + rank_c[e];
    csr[q] = make_int2(r, vb);
}

// ============ gather SpMM (bf16) + residual + LayerNorm ============
// One wave per dst row. 16 lanes x 16B (uint4) cover the 256B bf16 row;
// 4 edge-subgroups -> 4 edges (1 KB) in flight per iteration; csr prefetched.
template<bool OUT_BF>
__global__ __launch_bounds__(256) void gather_ln_k(
    const uint4* __restrict__ srcU,  // table gathered by user rows
    const uint4* __restrict__ srcI,  // table gathered by item rows
    const uint4* __restrict__ resU, const uint4* __restrict__ resI, // bf16 residual
    void* __restrict__ outU, void* __restrict__ outI,
    const int* __restrict__ rowptr, const int2* __restrict__ csr,
    const float* __restrict__ gamma, const float* __restrict__ beta,
    int nu, int N)
{
    int w = blockIdx.x * 4 + (threadIdx.x >> 6);
    if (w >= N) return;
    int lane = threadIdx.x & 63;
    int sub  = lane >> 4;   // edge slot 0..3
    int l16  = lane & 15;   // 16B chunk in row -> channels l16*8 .. +7

    const uint4* tbl;
    const uint4* res;
    void* out;
    if (w < nu) {
        tbl = srcU;
        res = resU + (ll)w * 16;
        out = OUT_BF ? (void*)((uint4*)outU + (ll)w * 16)
                     : (void*)((float4*)outU + (ll)w * 32);
    } else {
        int k = w - nu;
        tbl = srcI;
        res = resI + (ll)k * 16;
        out = OUT_BF ? (void*)((uint4*)outI + (ll)k * 16)
                     : (void*)((float4*)outI + (ll)k * 32);
    }

    int start = rowptr[w];
    int end   = rowptr[w + 1];

    float a0=0.f,a1=0.f,a2=0.f,a3=0.f,a4=0.f,a5=0.f,a6=0.f,a7=0.f;

    if (start < end) {
        int i0 = start + sub;
        int2 ec = csr[i0 < end ? i0 : end - 1];
        for (int j = start; j < end; j += 4) {
            int2 en;
            int jn = j + 4;
            if (jn < end) {                       // wave-uniform branch
                int i1 = jn + sub;
                en = csr[i1 < end ? i1 : end - 1]; // prefetch next iter
            }
            float v = ((j + sub) < end) ? __int_as_float(ec.y) : 0.0f;
            uint4 q = tbl[(((uint)ec.x) << 4) + l16];
            a0 += v * unpack_lo(q.x); a1 += v * unpack_hi(q.x);
            a2 += v * unpack_lo(q.y); a3 += v * unpack_hi(q.y);
            a4 += v * unpack_lo(q.z); a5 += v * unpack_hi(q.z);
            a6 += v * unpack_lo(q.w); a7 += v * unpack_hi(q.w);
            ec = en;
        }
    }

    // merge the 4 edge-subgroups (lanes l16, +16, +32, +48 hold same channels)
#define MRG(x) x += __shfl_xor(x, 16, 64); x += __shfl_xor(x, 32, 64)
    MRG(a0); MRG(a1); MRG(a2); MRG(a3); MRG(a4); MRG(a5); MRG(a6); MRG(a7);
#undef MRG

    // residual (bf16 row, broadcast across subgroups)
    uint4 r = res[l16];
    a0 += unpack_lo(r.x); a1 += unpack_hi(r.x);
    a2 += unpack_lo(r.y); a3 += unpack_hi(r.y);
    a4 += unpack_lo(r.z); a5 += unpack_hi(r.z);
    a6 += unpack_lo(r.w); a7 += unpack_hi(r.w);

    // LN stats: sum over the 16-lane group (channels unique within group)
    float s  = a0+a1+a2+a3+a4+a5+a6+a7;
    float ss = a0*a0+a1*a1+a2*a2+a3*a3+a4*a4+a5*a5+a6*a6+a7*a7;
#pragma unroll
    for (int off = 8; off > 0; off >>= 1) {
        s  += __shfl_xor(s, off, 64);
        ss += __shfl_xor(ss, off, 64);
    }
    float m   = s * (1.0f / 128.0f);
    float var = ss * (1.0f / 128.0f) - m * m;
    float inv = rsqrtf(var + EPS);

    float4 g0 = ((const float4*)gamma)[l16 * 2];
    float4 g1 = ((const float4*)gamma)[l16 * 2 + 1];
    float4 b0 = ((const float4*)beta)[l16 * 2];
    float4 b1 = ((const float4*)beta)[l16 * 2 + 1];
    float o0 = g0.x * (a0 - m) * inv + b0.x;
    float o1 = g0.y * (a1 - m) * inv + b0.y;
    float o2 = g0.z * (a2 - m) * inv + b0.z;
    float o3 = g0.w * (a3 - m) * inv + b0.w;
    float o4 = g1.x * (a4 - m) * inv + b1.x;
    float o5 = g1.y * (a5 - m) * inv + b1.y;
    float o6 = g1.z * (a6 - m) * inv + b1.z;
    float o7 = g1.w * (a7 - m) * inv + b1.w;

    if (sub == 0) {
        if (OUT_BF) {
            uint4 q;
            q.x = pack2(o0, o1); q.y = pack2(o2, o3);
            q.z = pack2(o4, o5); q.w = pack2(o6, o7);
            ((uint4*)out)[l16] = q;
        } else {
            ((float4*)out)[l16 * 2]     = make_float4(o0, o1, o2, o3);
            ((float4*)out)[l16 * 2 + 1] = make_float4(o4, o5, o6, o7);
        }
    }
}

extern "C" void kernel_launch(void* const* d_in, const int* in_sizes, int n_in,
                              void* d_out, int out_size, void* d_ws, size_t ws_size,
                              hipStream_t stream)
{
    const float* user_emb = (const float*)d_in[0];
    const float* item_emb = (const float*)d_in[1];
    const float* vals     = (const float*)d_in[2];
    const float* gamma    = (const float*)d_in[3];
    const float* beta     = (const float*)d_in[4];
    const int*   rows     = (const int*)d_in[5];
    const int*   cols     = (const int*)d_in[6];

    const int nu = in_sizes[0] / 128;   // 100000
    const int ni = in_sizes[1] / 128;   // 200000
    const int ne = in_sizes[2];         // 2000000
    const int N  = nu + ni;
    const int total = 2 * ne;

    float* dout   = (float*)d_out;
    float* dout_u = dout;
    float* dout_i = dout + (ll)nu * 128;

    // bf16 input tables live in d_out until layer 2 overwrites it
    uint* bf_u = (uint*)d_out;                 // nu*64 uints (25.6 MB)
    uint* bf_i = bf_u + (ll)nu * 64;           // ni*64 uints (51.2 MB)

    // ---- workspace layout (~127 MB, unchanged footprint) ----
    // cnt is now line-padded (N * CNT_STRIDE ints = 38.4 MB) and ALIASES the
    // wu_out/wi_out region: cnt is dead after scanA, wu/wi are first written
    // by the layer-1 gather (strictly later on the same stream).
    const int Npad = ((N + 1 + 255) & ~255);
    int*  rowptr    = (int*)d_ws;              // Npad (incl sentinel)
    int*  blockpart = rowptr + Npad;           // 512
    int*  rank_r    = blockpart + 512;         // ne
    int*  rank_c    = rank_r + ne;             // ne
    int2* csr       = (int2*)(rank_c + ne);            // total entries, 32 MB
    uint* wu_out    = (uint*)(csr + total);            // nu*64, 25.6 MB
    uint* wi_out    = wu_out + (ll)nu * 64;            // ni*64, 51.2 MB
    int*  cnt       = (int*)wu_out;            // N * CNT_STRIDE ints (aliased)

    const int cb   = (ne + 255) / 256;
    const int nbA  = (N + 1023) / 1024;
    const int nbC  = (N + 255) / 256;
    const int totT = (nu + ni) * 16;
    const int tb   = (totT + 255) / 256;

    // ---- CSR count/rank + bf16 conversion, fused ----
    hipMemsetAsync(cnt, 0, (size_t)N * CNT_STRIDE * sizeof(int), stream);
    prep_kernel<<<cb + tb, 256, 0, stream>>>(rows, cols, cnt, rank_r, rank_c,
                                             ne, nu, cb,
                                             user_emb, item_emb,
                                             (uint4*)bf_u, nu * 16, totT);
    scanA<<<nbA, 256, 0, stream>>>(cnt, rowptr, blockpart, N);
    scanB<<<1, 512, 0, stream>>>(blockpart, nbA);
    scanC<<<nbC, 256, 0, stream>>>(rowptr, blockpart, N, total);
    fill_kernel<<<cb, 256, 0, stream>>>(rows, cols, vals, rowptr, rank_r, rank_c,
                                        csr, ne, nu);

    const int gblocks = (N + 3) / 4;

    // ---- layer 1: gather bf16 input tables (d_out), bf16 residual (d_out),
    //      write bf16 layer-1 outputs (ws) ----
    gather_ln_k<true><<<gblocks, 256, 0, stream>>>(
        (const uint4*)bf_i, (const uint4*)bf_u,
        (const uint4*)bf_u, (const uint4*)bf_i,
        wu_out, wi_out,
        rowptr, csr, gamma, beta, nu, N);

    // ---- layer 2: gather bf16 L1 outs (ws), bf16 residuals (ws),
    //      write f32 finals (d_out) ----
    gather_ln_k<false><<<gblocks, 256, 0, stream>>>(
        (const uint4*)wi_out, (const uint4*)wu_out,
        (const uint4*)wu_out, (const uint4*)wi_out,
        dout_u, dout_i,
        rowptr, csr, gamma, beta, nu, N);
}

// Round 2
// 798.727 us; speedup vs baseline: 1.1845x; 1.1845x over previous
//
#include <hip/hip_runtime.h>

#define EPS 1e-5f
typedef long long ll;
typedef unsigned int uint;

// ---- counting-sort geometry ----
// coarse bin = bucket >> 8  (256 fine buckets per bin)
// chunks of 16384 items; counts matrix counts[bin][chunk] with chunk dim padded to 256
#define CHUNK   16384
#define NCPAD   256
#define NBMAX   2048

__device__ __forceinline__ uint bf_round(float x) {
    uint u = __float_as_uint(x);
    return (u + 0x7FFFu + ((u >> 16) & 1u)) >> 16;
}
__device__ __forceinline__ uint pack2(float a, float b) {
    return bf_round(a) | (bf_round(b) << 16);
}
__device__ __forceinline__ float unpack_lo(uint u) { return __uint_as_float(u << 16); }
__device__ __forceinline__ float unpack_hi(uint u) { return __uint_as_float(u & 0xFFFF0000u); }

// ---- P1: blocks [0,hb) LDS-histogram coarse bins; blocks [hb,hb+tb) f32->bf16 ----
__global__ __launch_bounds__(256) void hist_conv_k(
    const int* __restrict__ rows, const int* __restrict__ cols,
    int* __restrict__ counts, int ne, int nu, int NB, int hb,
    const float* __restrict__ ue, const float* __restrict__ ie,
    uint4* __restrict__ bfout, int nuT, int totT)
{
    int b = blockIdx.x;
    if (b < hb) {
        __shared__ int hist[NBMAX];
        for (int i = threadIdx.x; i < NB; i += 256) hist[i] = 0;
        __syncthreads();
        ll base0 = (ll)b * CHUNK;
        ll items = 2LL * ne;
        int n2 = (int)min((ll)CHUNK, items - base0);
        for (int k = threadIdx.x; k < n2; k += 256) {
            ll e = base0 + k;
            int bucket = (e < ne) ? rows[e] : nu + cols[e - ne];
            atomicAdd(&hist[bucket >> 8], 1);
        }
        __syncthreads();
        for (int i = threadIdx.x; i < NB; i += 256)
            counts[(ll)i * NCPAD + b] = hist[i];
    } else {
        int t = (b - hb) * 256 + threadIdx.x;
        if (t < totT) {
            const float4* src = (t < nuT) ? (const float4*)(ue + (ll)t * 8)
                                          : (const float4*)(ie + (ll)(t - nuT) * 8);
            float4 f0 = src[0], f1 = src[1];
            uint4 q;
            q.x = pack2(f0.x, f0.y); q.y = pack2(f0.z, f0.w);
            q.z = pack2(f1.x, f1.y); q.w = pack2(f1.z, f1.w);
            bfout[t] = q;
        }
    }
}

// ---- S1: per-bin exclusive scan over chunks; emits bin totals ----
__global__ __launch_bounds__(256) void s1_kernel(
    const int* __restrict__ counts, int* __restrict__ base,
    int* __restrict__ binT, int nchunk)
{
    int b = blockIdx.x;
    int t = threadIdx.x;
    int v = (t < nchunk) ? counts[(ll)b * NCPAD + t] : 0;
    __shared__ int sm[256];
    sm[t] = v; __syncthreads();
    for (int off = 1; off < 256; off <<= 1) {
        int a = (t >= off) ? sm[t - off] : 0;
        __syncthreads();
        sm[t] += a;
        __syncthreads();
    }
    base[(ll)b * NCPAD + t] = sm[t] - v;
    if (t == 255) binT[b] = sm[255];
}

// ---- S2: single-block exclusive scan of bin totals -> binptr ----
__global__ __launch_bounds__(256) void s2_kernel(
    const int* __restrict__ binT, int* __restrict__ binptr,
    int* __restrict__ rowptr, int NB, int Nrow, int total)
{
    __shared__ int sm[256];
    int t = threadIdx.x;
    const int PER = NBMAX / 256; // 8
    int loc[PER]; int s = 0;
#pragma unroll
    for (int k = 0; k < PER; k++) {
        int i = t * PER + k;
        loc[k] = (i < NB) ? binT[i] : 0;
        s += loc[k];
    }
    sm[t] = s; __syncthreads();
    for (int off = 1; off < 256; off <<= 1) {
        int a = (t >= off) ? sm[t - off] : 0;
        __syncthreads();
        sm[t] += a;
        __syncthreads();
    }
    int run = sm[t] - s;
#pragma unroll
    for (int k = 0; k < PER; k++) {
        int i = t * PER + k;
        if (i < NB) binptr[i] = run;
        run += loc[k];
    }
    if (t == 0) { binptr[NB] = total; rowptr[Nrow] = total; }
}

// ---- P2: scatter items into bin-major tmp via LDS cursors (no global atomics) ----
__global__ __launch_bounds__(256) void p2_kernel(
    const int* __restrict__ rows, const int* __restrict__ cols,
    const float* __restrict__ vals,
    const int* __restrict__ base, const int* __restrict__ binptr,
    int4* __restrict__ tmp, int ne, int nu, int NB)
{
    __shared__ int cur[NBMAX];
    int c = blockIdx.x;
    for (int i = threadIdx.x; i < NB; i += 256)
        cur[i] = binptr[i] + base[(ll)i * NCPAD + c];
    __syncthreads();
    ll base0 = (ll)c * CHUNK;
    ll items = 2LL * ne;
    int n2 = (int)min((ll)CHUNK, items - base0);
    for (int k = threadIdx.x; k < n2; k += 256) {
        ll e = base0 + k;
        int bucket, src; float v;
        if (e < ne) { bucket = rows[e]; src = cols[e]; v = vals[e]; }
        else        { ll e2 = e - ne; bucket = nu + cols[e2]; src = rows[e2]; v = vals[e2]; }
        int slot = atomicAdd(&cur[bucket >> 8], 1);
        tmp[slot] = make_int4(bucket, src, __float_as_int(v), 0);
    }
}

// ---- P3: per-bin fine rank (LDS), write rowptr (coalesced) + csr (bin-local) ----
__global__ __launch_bounds__(256) void p3_kernel(
    const int4* __restrict__ tmp, const int* __restrict__ binptr,
    int* __restrict__ rowptr, int2* __restrict__ csr)
{
    __shared__ int hist[256];
    __shared__ int sm[256];
    __shared__ int fineExcl[256];
    int b = blockIdx.x;
    int t = threadIdx.x;
    int s0 = binptr[b], s1 = binptr[b + 1];
    hist[t] = 0; __syncthreads();
    for (int i = s0 + t; i < s1; i += 256) {
        int4 it = tmp[i];
        atomicAdd(&hist[it.x & 255], 1);
    }
    __syncthreads();
    int v = hist[t];
    sm[t] = v; __syncthreads();
    for (int off = 1; off < 256; off <<= 1) {
        int a = (t >= off) ? sm[t - off] : 0;
        __syncthreads();
        sm[t] += a;
        __syncthreads();
    }
    fineExcl[t] = sm[t] - v;
    __syncthreads();
    // rowptr for the 256 buckets of this bin (padded array: always safe to write)
    rowptr[(b << 8) + t] = s0 + fineExcl[t];
    hist[t] = fineExcl[t];   // reuse as cursor
    __syncthreads();
    for (int i = s0 + t; i < s1; i += 256) {
        int4 it = tmp[i];
        int r = atomicAdd(&hist[it.x & 255], 1);
        csr[s0 + r] = make_int2(it.y, it.z);
    }
}

// ============ gather SpMM (bf16) + residual + LayerNorm ============
template<bool OUT_BF>
__global__ __launch_bounds__(256) void gather_ln_k(
    const uint4* __restrict__ srcU,  // table gathered by user rows
    const uint4* __restrict__ srcI,  // table gathered by item rows
    const uint4* __restrict__ resU, const uint4* __restrict__ resI, // bf16 residual
    void* __restrict__ outU, void* __restrict__ outI,
    const int* __restrict__ rowptr, const int2* __restrict__ csr,
    const float* __restrict__ gamma, const float* __restrict__ beta,
    int nu, int N)
{
    int w = blockIdx.x * 4 + (threadIdx.x >> 6);
    if (w >= N) return;
    int lane = threadIdx.x & 63;
    int sub  = lane >> 4;   // edge slot 0..3
    int l16  = lane & 15;   // 16B chunk in row -> channels l16*8 .. +7

    const uint4* tbl;
    const uint4* res;
    void* out;
    if (w < nu) {
        tbl = srcU;
        res = resU + (ll)w * 16;
        out = OUT_BF ? (void*)((uint4*)outU + (ll)w * 16)
                     : (void*)((float4*)outU + (ll)w * 32);
    } else {
        int k = w - nu;
        tbl = srcI;
        res = resI + (ll)k * 16;
        out = OUT_BF ? (void*)((uint4*)outI + (ll)k * 16)
                     : (void*)((float4*)outI + (ll)k * 32);
    }

    int start = rowptr[w];
    int end   = rowptr[w + 1];

    float a0=0.f,a1=0.f,a2=0.f,a3=0.f,a4=0.f,a5=0.f,a6=0.f,a7=0.f;

    if (start < end) {
        int i0 = start + sub;
        int2 ec = csr[i0 < end ? i0 : end - 1];
        for (int j = start; j < end; j += 4) {
            int2 en;
            int jn = j + 4;
            if (jn < end) {                       // wave-uniform branch
                int i1 = jn + sub;
                en = csr[i1 < end ? i1 : end - 1]; // prefetch next iter
            }
            float v = ((j + sub) < end) ? __int_as_float(ec.y) : 0.0f;
            uint4 q = tbl[(((uint)ec.x) << 4) + l16];
            a0 += v * unpack_lo(q.x); a1 += v * unpack_hi(q.x);
            a2 += v * unpack_lo(q.y); a3 += v * unpack_hi(q.y);
            a4 += v * unpack_lo(q.z); a5 += v * unpack_hi(q.z);
            a6 += v * unpack_lo(q.w); a7 += v * unpack_hi(q.w);
            ec = en;
        }
    }

    // merge the 4 edge-subgroups (lanes l16, +16, +32, +48 hold same channels)
#define MRG(x) x += __shfl_xor(x, 16, 64); x += __shfl_xor(x, 32, 64)
    MRG(a0); MRG(a1); MRG(a2); MRG(a3); MRG(a4); MRG(a5); MRG(a6); MRG(a7);
#undef MRG

    // residual (bf16 row, broadcast across subgroups)
    uint4 r = res[l16];
    a0 += unpack_lo(r.x); a1 += unpack_hi(r.x);
    a2 += unpack_lo(r.y); a3 += unpack_hi(r.y);
    a4 += unpack_lo(r.z); a5 += unpack_hi(r.z);
    a6 += unpack_lo(r.w); a7 += unpack_hi(r.w);

    // LN stats: sum over the 16-lane group (channels unique within group)
    float s  = a0+a1+a2+a3+a4+a5+a6+a7;
    float ss = a0*a0+a1*a1+a2*a2+a3*a3+a4*a4+a5*a5+a6*a6+a7*a7;
#pragma unroll
    for (int off = 8; off > 0; off >>= 1) {
        s  += __shfl_xor(s, off, 64);
        ss += __shfl_xor(ss, off, 64);
    }
    float m   = s * (1.0f / 128.0f);
    float var = ss * (1.0f / 128.0f) - m * m;
    float inv = rsqrtf(var + EPS);

    float4 g0 = ((const float4*)gamma)[l16 * 2];
    float4 g1 = ((const float4*)gamma)[l16 * 2 + 1];
    float4 b0 = ((const float4*)beta)[l16 * 2];
    float4 b1 = ((const float4*)beta)[l16 * 2 + 1];
    float o0 = g0.x * (a0 - m) * inv + b0.x;
    float o1 = g0.y * (a1 - m) * inv + b0.y;
    float o2 = g0.z * (a2 - m) * inv + b0.z;
    float o3 = g0.w * (a3 - m) * inv + b0.w;
    float o4 = g1.x * (a4 - m) * inv + b1.x;
    float o5 = g1.y * (a5 - m) * inv + b1.y;
    float o6 = g1.z * (a6 - m) * inv + b1.z;
    float o7 = g1.w * (a7 - m) * inv + b1.w;

    if (sub == 0) {
        if (OUT_BF) {
            uint4 q;
            q.x = pack2(o0, o1); q.y = pack2(o2, o3);
            q.z = pack2(o4, o5); q.w = pack2(o6, o7);
            ((uint4*)out)[l16] = q;
        } else {
            ((float4*)out)[l16 * 2]     = make_float4(o0, o1, o2, o3);
            ((float4*)out)[l16 * 2 + 1] = make_float4(o4, o5, o6, o7);
        }
    }
}

extern "C" void kernel_launch(void* const* d_in, const int* in_sizes, int n_in,
                              void* d_out, int out_size, void* d_ws, size_t ws_size,
                              hipStream_t stream)
{
    const float* user_emb = (const float*)d_in[0];
    const float* item_emb = (const float*)d_in[1];
    const float* vals     = (const float*)d_in[2];
    const float* gamma    = (const float*)d_in[3];
    const float* beta     = (const float*)d_in[4];
    const int*   rows     = (const int*)d_in[5];
    const int*   cols     = (const int*)d_in[6];

    const int nu = in_sizes[0] / 128;   // 100000
    const int ni = in_sizes[1] / 128;   // 200000
    const int ne = in_sizes[2];         // 2000000
    const int N  = nu + ni;
    const int total = 2 * ne;

    float* dout   = (float*)d_out;
    float* dout_u = dout;
    float* dout_i = dout + (ll)nu * 128;

    // bf16 input tables live in d_out until layer 2 overwrites it
    uint* bf_u = (uint*)d_out;                 // nu*64 uints (25.6 MB)
    uint* bf_i = bf_u + (ll)nu * 64;           // ni*64 uints (51.2 MB)

    // ---- geometry ----
    const int NB = (N + 255) >> 8;                       // 1172 coarse bins
    const int hb = (total + CHUNK - 1) / CHUNK;          // 245 chunks (<= NCPAD)

    // ---- workspace layout (~112 MB) ----
    // tmp (64 MB) aliases wu/wi (76.8 MB): tmp dies after p3, wu/wi born at gather-L1.
    int*  rowptr  = (int*)d_ws;                          // NB*256 ints (covers N+1 sentinel)
    int*  counts  = rowptr + (ll)NB * 256;               // NB*256
    int*  base    = counts + (ll)NB * 256;               // NB*256
    int*  binT    = base + (ll)NB * 256;                 // NBMAX
    int*  binptr  = binT + NBMAX;                        // NBMAX (NB+1 used)
    int2* csr     = (int2*)(binptr + NBMAX);             // total int2, 32 MB
    uint* wu_out  = (uint*)(csr + total);                // nu*64, 25.6 MB
    uint* wi_out  = wu_out + (ll)nu * 64;                // ni*64, 51.2 MB
    int4* tmp     = (int4*)wu_out;                       // total int4, 64 MB (aliased)

    const int totT = (nu + ni) * 16;
    const int tb   = (totT + 255) / 256;

    // ---- CSR build: LDS-atomic counting sort (no device-scope atomics) ----
    hist_conv_k<<<hb + tb, 256, 0, stream>>>(rows, cols, counts, ne, nu, NB, hb,
                                             user_emb, item_emb,
                                             (uint4*)bf_u, nu * 16, totT);
    s1_kernel<<<NB, 256, 0, stream>>>(counts, base, binT, hb);
    s2_kernel<<<1, 256, 0, stream>>>(binT, binptr, rowptr, NB, N, total);
    p2_kernel<<<hb, 256, 0, stream>>>(rows, cols, vals, base, binptr, tmp, ne, nu, NB);
    p3_kernel<<<NB, 256, 0, stream>>>(tmp, binptr, rowptr, csr);

    const int gblocks = (N + 3) / 4;

    // ---- layer 1: gather bf16 input tables (d_out), bf16 residual (d_out),
    //      write bf16 layer-1 outputs (ws) ----
    gather_ln_k<true><<<gblocks, 256, 0, stream>>>(
        (const uint4*)bf_i, (const uint4*)bf_u,
        (const uint4*)bf_u, (const uint4*)bf_i,
        wu_out, wi_out,
        rowptr, csr, gamma, beta, nu, N);

    // ---- layer 2: gather bf16 L1 outs (ws), bf16 residuals (ws),
    //      write f32 finals (d_out) ----
    gather_ln_k<false><<<gblocks, 256, 0, stream>>>(
        (const uint4*)wi_out, (const uint4*)wu_out,
        (const uint4*)wu_out, (const uint4*)wi_out,
        dout_u, dout_i,
        rowptr, csr, gamma, beta, nu, N);
}

// Round 3
// 741.910 us; speedup vs baseline: 1.2752x; 1.0766x over previous
//
#include <hip/hip_runtime.h>

#define EPS 1e-5f
typedef long long ll;
typedef unsigned int uint;
typedef float f32x2 __attribute__((ext_vector_type(2)));

// ---- counting-sort geometry ----
// coarse bin = bucket >> 8 (256 fine buckets per bin)
// chunks of 8192 items; counts[bin][chunk], chunk dim padded to NCPAD
#define CHUNK   8192
#define NCPAD   512
#define NBMAX   2048
#define P3CAP   8192   // LDS staging capacity (int2) in p3

__device__ __forceinline__ uint bf_round(float x) {
    uint u = __float_as_uint(x);
    return (u + 0x7FFFu + ((u >> 16) & 1u)) >> 16;
}
__device__ __forceinline__ uint pack2(float a, float b) {
    return bf_round(a) | (bf_round(b) << 16);
}
__device__ __forceinline__ float unpack_lo(uint u) { return __uint_as_float(u << 16); }
__device__ __forceinline__ float unpack_hi(uint u) { return __uint_as_float(u & 0xFFFF0000u); }

// ---- P1: blocks [0,hb) LDS-histogram coarse bins; blocks [hb,hb+tb) f32->bf16 ----
__global__ __launch_bounds__(256) void hist_conv_k(
    const int* __restrict__ rows, const int* __restrict__ cols,
    int* __restrict__ counts, int ne, int nu, int NB, int hb,
    const float* __restrict__ ue, const float* __restrict__ ie,
    uint4* __restrict__ bfout, int nuT, int totT)
{
    int b = blockIdx.x;
    if (b < hb) {
        __shared__ int hist[NBMAX];
        for (int i = threadIdx.x; i < NB; i += 256) hist[i] = 0;
        __syncthreads();
        ll base0 = (ll)b * CHUNK;
        ll items = 2LL * ne;
        int n2 = (int)min((ll)CHUNK, items - base0);
        for (int k = threadIdx.x; k < n2; k += 256) {
            ll e = base0 + k;
            int bucket = (e < ne) ? rows[e] : nu + cols[e - ne];
            atomicAdd(&hist[bucket >> 8], 1);
        }
        __syncthreads();
        for (int i = threadIdx.x; i < NB; i += 256)
            counts[(ll)i * NCPAD + b] = hist[i];
    } else {
        int t = (b - hb) * 256 + threadIdx.x;
        if (t < totT) {
            const float4* src = (t < nuT) ? (const float4*)(ue + (ll)t * 8)
                                          : (const float4*)(ie + (ll)(t - nuT) * 8);
            float4 f0 = src[0], f1 = src[1];
            uint4 q;
            q.x = pack2(f0.x, f0.y); q.y = pack2(f0.z, f0.w);
            q.z = pack2(f1.x, f1.y); q.w = pack2(f1.z, f1.w);
            bfout[t] = q;
        }
    }
}

// ---- S1: per-bin exclusive scan over chunks (2 per thread); emits bin totals ----
__global__ __launch_bounds__(256) void s1_kernel(
    const int* __restrict__ counts, int* __restrict__ base,
    int* __restrict__ binT, int nchunk)
{
    int b = blockIdx.x;
    int t = threadIdx.x;
    int i0 = 2 * t, i1 = 2 * t + 1;
    int v0 = (i0 < nchunk) ? counts[(ll)b * NCPAD + i0] : 0;
    int v1 = (i1 < nchunk) ? counts[(ll)b * NCPAD + i1] : 0;
    int s = v0 + v1;
    __shared__ int sm[256];
    sm[t] = s; __syncthreads();
    for (int off = 1; off < 256; off <<= 1) {
        int a = (t >= off) ? sm[t - off] : 0;
        __syncthreads();
        sm[t] += a;
        __syncthreads();
    }
    int excl = sm[t] - s;
    base[(ll)b * NCPAD + i0] = excl;
    base[(ll)b * NCPAD + i1] = excl + v0;
    if (t == 255) binT[b] = sm[255];
}

// ---- S2: single-block exclusive scan of bin totals -> binptr ----
__global__ __launch_bounds__(256) void s2_kernel(
    const int* __restrict__ binT, int* __restrict__ binptr,
    int* __restrict__ rowptr, int NB, int Nrow, int total)
{
    __shared__ int sm[256];
    int t = threadIdx.x;
    const int PER = NBMAX / 256; // 8
    int loc[PER]; int s = 0;
#pragma unroll
    for (int k = 0; k < PER; k++) {
        int i = t * PER + k;
        loc[k] = (i < NB) ? binT[i] : 0;
        s += loc[k];
    }
    sm[t] = s; __syncthreads();
    for (int off = 1; off < 256; off <<= 1) {
        int a = (t >= off) ? sm[t - off] : 0;
        __syncthreads();
        sm[t] += a;
        __syncthreads();
    }
    int run = sm[t] - s;
#pragma unroll
    for (int k = 0; k < PER; k++) {
        int i = t * PER + k;
        if (i < NB) binptr[i] = run;
        run += loc[k];
    }
    if (t == 0) { binptr[NB] = total; rowptr[Nrow] = total; }
}

// ---- P2: scatter 8B records into bin-major tmp via LDS cursors ----
__global__ __launch_bounds__(256) void p2_kernel(
    const int* __restrict__ rows, const int* __restrict__ cols,
    const float* __restrict__ vals,
    const int* __restrict__ base, const int* __restrict__ binptr,
    int2* __restrict__ tmp, int ne, int nu, int NB)
{
    __shared__ int cur[NBMAX];
    int c = blockIdx.x;
    for (int i = threadIdx.x; i < NB; i += 256)
        cur[i] = binptr[i] + base[(ll)i * NCPAD + c];
    __syncthreads();
    ll base0 = (ll)c * CHUNK;
    ll items = 2LL * ne;
    int n2 = (int)min((ll)CHUNK, items - base0);
    for (int k = threadIdx.x; k < n2; k += 256) {
        ll e = base0 + k;
        int bucket, src; float v;
        if (e < ne) { bucket = rows[e]; src = cols[e]; v = vals[e]; }
        else        { ll e2 = e - ne; bucket = nu + cols[e2]; src = rows[e2]; v = vals[e2]; }
        int slot = atomicAdd(&cur[bucket >> 8], 1);
        // key = fine-bucket (8b) << 24 | src (src < 2^24)
        tmp[slot] = make_int2(((bucket & 255) << 24) | src, __float_as_int(v));
    }
}

// ---- P3: per-bin fine rank; single pass with LDS staging (fallback: 2-pass) ----
__global__ __launch_bounds__(256) void p3_kernel(
    const int2* __restrict__ tmp, const int* __restrict__ binptr,
    int* __restrict__ rowptr, int2* __restrict__ csr)
{
    __shared__ int hist[256];
    __shared__ int sm[256];
    __shared__ int2 stage[P3CAP];   // 64 KB
    int b = blockIdx.x;
    int t = threadIdx.x;
    int s0 = binptr[b], s1 = binptr[b + 1];
    int n = s1 - s0;
    bool inLds = (n <= P3CAP);      // wave-uniform
    hist[t] = 0; __syncthreads();
    if (inLds) {
        for (int i = t; i < n; i += 256) {
            int2 it = tmp[s0 + i];
            stage[i] = it;
            atomicAdd(&hist[(uint)it.x >> 24], 1);
        }
    } else {
        for (int i = t; i < n; i += 256)
            atomicAdd(&hist[(uint)tmp[s0 + i].x >> 24], 1);
    }
    __syncthreads();
    int v = hist[t];
    sm[t] = v; __syncthreads();
    for (int off = 1; off < 256; off <<= 1) {
        int a = (t >= off) ? sm[t - off] : 0;
        __syncthreads();
        sm[t] += a;
        __syncthreads();
    }
    int excl = sm[t] - v;
    __syncthreads();
    rowptr[(b << 8) + t] = s0 + excl;   // padded rowptr: always safe
    hist[t] = excl;                      // reuse as cursor
    __syncthreads();
    if (inLds) {
        for (int i = t; i < n; i += 256) {
            int2 it = stage[i];
            int r = atomicAdd(&hist[(uint)it.x >> 24], 1);
            csr[s0 + r] = make_int2(it.x & 0xFFFFFF, it.y);
        }
    } else {
        for (int i = t; i < n; i += 256) {
            int2 it = tmp[s0 + i];
            int r = atomicAdd(&hist[(uint)it.x >> 24], 1);
            csr[s0 + r] = make_int2(it.x & 0xFFFFFF, it.y);
        }
    }
}

// ============ gather SpMM (bf16) + residual + LayerNorm ============
// One wave per dst row; 4 edge-subgroups x 16 lanes x 16B.
// Software-pipelined: csr prefetched 2 tiles ahead, tbl gather 1 tile ahead.
template<bool OUT_BF>
__global__ __launch_bounds__(256) void gather_ln_k(
    const uint4* __restrict__ srcU, const uint4* __restrict__ srcI,
    const uint4* __restrict__ resU, const uint4* __restrict__ resI,
    void* __restrict__ outU, void* __restrict__ outI,
    const int* __restrict__ rowptr, const int2* __restrict__ csr,
    const float* __restrict__ gamma, const float* __restrict__ beta,
    int nu, int N)
{
    int w = blockIdx.x * 4 + (threadIdx.x >> 6);
    if (w >= N) return;
    int lane = threadIdx.x & 63;
    int sub  = lane >> 4;   // edge slot 0..3
    int l16  = lane & 15;   // 16B chunk in row

    const uint4* tbl;
    const uint4* res;
    void* out;
    if (w < nu) {
        tbl = srcU;
        res = resU + (ll)w * 16;
        out = OUT_BF ? (void*)((uint4*)outU + (ll)w * 16)
                     : (void*)((float4*)outU + (ll)w * 32);
    } else {
        int k = w - nu;
        tbl = srcI;
        res = resI + (ll)k * 16;
        out = OUT_BF ? (void*)((uint4*)outI + (ll)k * 16)
                     : (void*)((float4*)outI + (ll)k * 32);
    }

    int start = rowptr[w];
    int end   = rowptr[w + 1];

    f32x2 a01 = {0.f, 0.f}, a23 = {0.f, 0.f}, a45 = {0.f, 0.f}, a67 = {0.f, 0.f};

#define FMA8(q, vv) {                                                   \
        f32x2 b;                                                        \
        b[0] = unpack_lo(q.x); b[1] = unpack_hi(q.x); a01 = vv * b + a01; \
        b[0] = unpack_lo(q.y); b[1] = unpack_hi(q.y); a23 = vv * b + a23; \
        b[0] = unpack_lo(q.z); b[1] = unpack_hi(q.z); a45 = vv * b + a45; \
        b[0] = unpack_lo(q.w); b[1] = unpack_hi(q.w); a67 = vv * b + a67; }

    if (start < end) {
        // prologue: tile0 csr + gather in flight, tile1 csr in flight
        int i0 = start + sub;
        int2 ecC = csr[i0 < end ? i0 : end - 1];
        int2 ecN = ecC;
        if (start + 4 < end) {
            int i1 = start + 4 + sub;
            ecN = csr[i1 < end ? i1 : end - 1];
        }
        uint4 qC = tbl[(((uint)ecC.x) << 4) + l16];

        int j = start;
        for (; j + 4 < end; j += 4) {
            // csr prefetch tile t+2 (wave-uniform branch)
            int jnn = j + 8;
            int2 ecF = ecN;
            if (jnn < end) {
                int i2 = jnn + sub;
                ecF = csr[i2 < end ? i2 : end - 1];
            }
            // tbl gather tile t+1 (ecN ready since last iter)
            uint4 qN = tbl[(((uint)ecN.x) << 4) + l16];
            // compute tile t: all 4 slots valid (j+3 < j+4 <= end-? j+4<end)
            float v = __int_as_float(ecC.y);
            f32x2 vv = {v, v};
            FMA8(qC, vv);
            ecC = ecN; ecN = ecF; qC = qN;
        }
        // final (possibly partial) tile
        {
            float v = ((j + sub) < end) ? __int_as_float(ecC.y) : 0.0f;
            f32x2 vv = {v, v};
            FMA8(qC, vv);
        }
    }
#undef FMA8

    float a0 = a01[0], a1 = a01[1], a2 = a23[0], a3 = a23[1];
    float a4 = a45[0], a5 = a45[1], a6 = a67[0], a7 = a67[1];

    // merge the 4 edge-subgroups
#define MRG(x) x += __shfl_xor(x, 16, 64); x += __shfl_xor(x, 32, 64)
    MRG(a0); MRG(a1); MRG(a2); MRG(a3); MRG(a4); MRG(a5); MRG(a6); MRG(a7);
#undef MRG

    // residual (bf16 row)
    uint4 r = res[l16];
    a0 += unpack_lo(r.x); a1 += unpack_hi(r.x);
    a2 += unpack_lo(r.y); a3 += unpack_hi(r.y);
    a4 += unpack_lo(r.z); a5 += unpack_hi(r.z);
    a6 += unpack_lo(r.w); a7 += unpack_hi(r.w);

    // LN stats over the 16-lane group
    float s  = a0+a1+a2+a3+a4+a5+a6+a7;
    float ss = a0*a0+a1*a1+a2*a2+a3*a3+a4*a4+a5*a5+a6*a6+a7*a7;
#pragma unroll
    for (int off = 8; off > 0; off >>= 1) {
        s  += __shfl_xor(s, off, 64);
        ss += __shfl_xor(ss, off, 64);
    }
    float m   = s * (1.0f / 128.0f);
    float var = ss * (1.0f / 128.0f) - m * m;
    float inv = rsqrtf(var + EPS);

    float4 g0 = ((const float4*)gamma)[l16 * 2];
    float4 g1 = ((const float4*)gamma)[l16 * 2 + 1];
    float4 b0 = ((const float4*)beta)[l16 * 2];
    float4 b1 = ((const float4*)beta)[l16 * 2 + 1];
    float o0 = g0.x * (a0 - m) * inv + b0.x;
    float o1 = g0.y * (a1 - m) * inv + b0.y;
    float o2 = g0.z * (a2 - m) * inv + b0.z;
    float o3 = g0.w * (a3 - m) * inv + b0.w;
    float o4 = g1.x * (a4 - m) * inv + b1.x;
    float o5 = g1.y * (a5 - m) * inv + b1.y;
    float o6 = g1.z * (a6 - m) * inv + b1.z;
    float o7 = g1.w * (a7 - m) * inv + b1.w;

    if (sub == 0) {
        if (OUT_BF) {
            uint4 q;
            q.x = pack2(o0, o1); q.y = pack2(o2, o3);
            q.z = pack2(o4, o5); q.w = pack2(o6, o7);
            ((uint4*)out)[l16] = q;
        } else {
            ((float4*)out)[l16 * 2]     = make_float4(o0, o1, o2, o3);
            ((float4*)out)[l16 * 2 + 1] = make_float4(o4, o5, o6, o7);
        }
    }
}

extern "C" void kernel_launch(void* const* d_in, const int* in_sizes, int n_in,
                              void* d_out, int out_size, void* d_ws, size_t ws_size,
                              hipStream_t stream)
{
    const float* user_emb = (const float*)d_in[0];
    const float* item_emb = (const float*)d_in[1];
    const float* vals     = (const float*)d_in[2];
    const float* gamma    = (const float*)d_in[3];
    const float* beta     = (const float*)d_in[4];
    const int*   rows     = (const int*)d_in[5];
    const int*   cols     = (const int*)d_in[6];

    const int nu = in_sizes[0] / 128;   // 100000
    const int ni = in_sizes[1] / 128;   // 200000
    const int ne = in_sizes[2];         // 2000000
    const int N  = nu + ni;
    const int total = 2 * ne;

    float* dout   = (float*)d_out;
    float* dout_u = dout;
    float* dout_i = dout + (ll)nu * 128;

    // bf16 input tables live in d_out until layer 2 overwrites it
    uint* bf_u = (uint*)d_out;                 // nu*64 uints (25.6 MB)
    uint* bf_i = bf_u + (ll)nu * 64;           // ni*64 uints (51.2 MB)

    // ---- geometry ----
    const int NB = (N + 255) >> 8;                       // 1172 coarse bins
    const int hb = (total + CHUNK - 1) / CHUNK;          // 489 chunks (<= NCPAD)

    // ---- workspace layout (~115 MB) ----
    // tmp (32 MB int2) aliases wu/wi (76.8 MB): tmp dies after p3.
    int*  rowptr  = (int*)d_ws;                          // NB*256 ints
    int*  counts  = rowptr + (ll)NB * 256;               // NB*NCPAD
    int*  base    = counts + (ll)NB * NCPAD;             // NB*NCPAD
    int*  binT    = base + (ll)NB * NCPAD;               // NBMAX
    int*  binptr  = binT + NBMAX;                        // NBMAX (NB+1 used)
    int2* csr     = (int2*)(binptr + NBMAX);             // total int2, 32 MB
    uint* wu_out  = (uint*)(csr + total);                // nu*64, 25.6 MB
    uint* wi_out  = wu_out + (ll)nu * 64;                // ni*64, 51.2 MB
    int2* tmp     = (int2*)wu_out;                       // total int2, 32 MB (aliased)

    const int totT = (nu + ni) * 16;
    const int tb   = (totT + 255) / 256;

    // ---- CSR build: LDS-atomic counting sort ----
    hist_conv_k<<<hb + tb, 256, 0, stream>>>(rows, cols, counts, ne, nu, NB, hb,
                                             user_emb, item_emb,
                                             (uint4*)bf_u, nu * 16, totT);
    s1_kernel<<<NB, 256, 0, stream>>>(counts, base, binT, hb);
    s2_kernel<<<1, 256, 0, stream>>>(binT, binptr, rowptr, NB, N, total);
    p2_kernel<<<hb, 256, 0, stream>>>(rows, cols, vals, base, binptr, tmp, ne, nu, NB);
    p3_kernel<<<NB, 256, 0, stream>>>(tmp, binptr, rowptr, csr);

    const int gblocks = (N + 3) / 4;

    // ---- layer 1 ----
    gather_ln_k<true><<<gblocks, 256, 0, stream>>>(
        (const uint4*)bf_i, (const uint4*)bf_u,
        (const uint4*)bf_u, (const uint4*)bf_i,
        wu_out, wi_out,
        rowptr, csr, gamma, beta, nu, N);

    // ---- layer 2 ----
    gather_ln_k<false><<<gblocks, 256, 0, stream>>>(
        (const uint4*)wi_out, (const uint4*)wu_out,
        (const uint4*)wu_out, (const uint4*)wi_out,
        dout_u, dout_i,
        rowptr, csr, gamma, beta, nu, N);
}

// Round 4
// 693.469 us; speedup vs baseline: 1.3642x; 1.0699x over previous
//
#include <hip/hip_runtime.h>

#define EPS 1e-5f
typedef long long ll;
typedef unsigned int uint;
typedef float f32x2 __attribute__((ext_vector_type(2)));

// ---- counting-sort geometry ----
// coarse bin = bucket >> 8 (256 fine buckets per bin)
// chunks of 4096 items; counts[bin][chunk], chunk dim padded to NCPAD
#define CHUNK   4096
#define NCPAD   1024
#define NBMAX   2048
#define P3CAP   8192   // LDS staging capacity (int2) in p3

__device__ __forceinline__ uint bf_round(float x) {
    uint u = __float_as_uint(x);
    return (u + 0x7FFFu + ((u >> 16) & 1u)) >> 16;
}
__device__ __forceinline__ uint pack2(float a, float b) {
    return bf_round(a) | (bf_round(b) << 16);
}
__device__ __forceinline__ float unpack_lo(uint u) { return __uint_as_float(u << 16); }
__device__ __forceinline__ float unpack_hi(uint u) { return __uint_as_float(u & 0xFFFF0000u); }

// ---- P1: blocks [0,hb) LDS-histogram coarse bins; blocks [hb,hb+tb) f32->bf16 ----
__global__ __launch_bounds__(256) void hist_conv_k(
    const int* __restrict__ rows, const int* __restrict__ cols,
    int* __restrict__ counts, int ne, int nu, int NB, int hb,
    const float* __restrict__ ue, const float* __restrict__ ie,
    uint4* __restrict__ bfout, int nuT, int totT)
{
    int b = blockIdx.x;
    if (b < hb) {
        __shared__ int hist[NBMAX];
        for (int i = threadIdx.x; i < NB; i += 256) hist[i] = 0;
        __syncthreads();
        ll base0 = (ll)b * CHUNK;
        ll items = 2LL * ne;
        int n2 = (int)min((ll)CHUNK, items - base0);
        for (int k = threadIdx.x; k < n2; k += 256) {
            ll e = base0 + k;
            int bucket = (e < ne) ? rows[e] : nu + cols[e - ne];
            atomicAdd(&hist[bucket >> 8], 1);
        }
        __syncthreads();
        for (int i = threadIdx.x; i < NB; i += 256)
            counts[(ll)i * NCPAD + b] = hist[i];
    } else {
        int t = (b - hb) * 256 + threadIdx.x;
        if (t < totT) {
            const float4* src = (t < nuT) ? (const float4*)(ue + (ll)t * 8)
                                          : (const float4*)(ie + (ll)(t - nuT) * 8);
            float4 f0 = src[0], f1 = src[1];
            uint4 q;
            q.x = pack2(f0.x, f0.y); q.y = pack2(f0.z, f0.w);
            q.z = pack2(f1.x, f1.y); q.w = pack2(f1.z, f1.w);
            bfout[t] = q;
        }
    }
}

// ---- S1: per-bin exclusive scan over chunks (4 per thread, int4); emits totals ----
__global__ __launch_bounds__(256) void s1_kernel(
    const int* __restrict__ counts, int* __restrict__ base,
    int* __restrict__ binT, int nchunk)
{
    int b = blockIdx.x;
    int t = threadIdx.x;
    int4 v = ((const int4*)(counts + (ll)b * NCPAD))[t];
    int i0 = 4 * t;
    if (i0 + 0 >= nchunk) v.x = 0;
    if (i0 + 1 >= nchunk) v.y = 0;
    if (i0 + 2 >= nchunk) v.z = 0;
    if (i0 + 3 >= nchunk) v.w = 0;
    int s = v.x + v.y + v.z + v.w;
    __shared__ int sm[256];
    sm[t] = s; __syncthreads();
    for (int off = 1; off < 256; off <<= 1) {
        int a = (t >= off) ? sm[t - off] : 0;
        __syncthreads();
        sm[t] += a;
        __syncthreads();
    }
    int excl = sm[t] - s;
    int4 o;
    o.x = excl; o.y = o.x + v.x; o.z = o.y + v.y; o.w = o.z + v.z;
    ((int4*)(base + (ll)b * NCPAD))[t] = o;
    if (t == 255) binT[b] = sm[255];
}

// ---- S2: single-block exclusive scan of bin totals -> binptr ----
__global__ __launch_bounds__(256) void s2_kernel(
    const int* __restrict__ binT, int* __restrict__ binptr,
    int* __restrict__ rowptr, int NB, int Nrow, int total)
{
    __shared__ int sm[256];
    int t = threadIdx.x;
    const int PER = NBMAX / 256; // 8
    int loc[PER]; int s = 0;
#pragma unroll
    for (int k = 0; k < PER; k++) {
        int i = t * PER + k;
        loc[k] = (i < NB) ? binT[i] : 0;
        s += loc[k];
    }
    sm[t] = s; __syncthreads();
    for (int off = 1; off < 256; off <<= 1) {
        int a = (t >= off) ? sm[t - off] : 0;
        __syncthreads();
        sm[t] += a;
        __syncthreads();
    }
    int run = sm[t] - s;
#pragma unroll
    for (int k = 0; k < PER; k++) {
        int i = t * PER + k;
        if (i < NB) binptr[i] = run;
        run += loc[k];
    }
    if (t == 0) { binptr[NB] = total; rowptr[Nrow] = total; }
}

// ---- P2: scatter 8B records into bin-major tmp via LDS cursors ----
__global__ __launch_bounds__(256) void p2_kernel(
    const int* __restrict__ rows, const int* __restrict__ cols,
    const float* __restrict__ vals,
    const int* __restrict__ base, const int* __restrict__ binptr,
    int2* __restrict__ tmp, int ne, int nu, int NB)
{
    __shared__ int cur[NBMAX];
    int c = blockIdx.x;
    for (int i = threadIdx.x; i < NB; i += 256)
        cur[i] = binptr[i] + base[(ll)i * NCPAD + c];
    __syncthreads();
    ll base0 = (ll)c * CHUNK;
    ll items = 2LL * ne;
    int n2 = (int)min((ll)CHUNK, items - base0);
    for (int k = threadIdx.x; k < n2; k += 256) {
        ll e = base0 + k;
        int bucket, src; float v;
        if (e < ne) { bucket = rows[e]; src = cols[e]; v = vals[e]; }
        else        { ll e2 = e - ne; bucket = nu + cols[e2]; src = rows[e2]; v = vals[e2]; }
        int slot = atomicAdd(&cur[bucket >> 8], 1);
        // key = fine-bucket (8b) << 24 | src (src < 2^24)
        tmp[slot] = make_int2(((bucket & 255) << 24) | src, __float_as_int(v));
    }
}

// ---- P3: per-bin fine rank; single pass with LDS staging (fallback: 2-pass) ----
__global__ __launch_bounds__(256) void p3_kernel(
    const int2* __restrict__ tmp, const int* __restrict__ binptr,
    int* __restrict__ rowptr, int2* __restrict__ csr)
{
    __shared__ int hist[256];
    __shared__ int sm[256];
    __shared__ int2 stage[P3CAP];   // 64 KB
    int b = blockIdx.x;
    int t = threadIdx.x;
    int s0 = binptr[b], s1 = binptr[b + 1];
    int n = s1 - s0;
    bool inLds = (n <= P3CAP);      // wave-uniform
    hist[t] = 0; __syncthreads();
    if (inLds) {
        for (int i = t; i < n; i += 256) {
            int2 it = tmp[s0 + i];
            stage[i] = it;
            atomicAdd(&hist[(uint)it.x >> 24], 1);
        }
    } else {
        for (int i = t; i < n; i += 256)
            atomicAdd(&hist[(uint)tmp[s0 + i].x >> 24], 1);
    }
    __syncthreads();
    int v = hist[t];
    sm[t] = v; __syncthreads();
    for (int off = 1; off < 256; off <<= 1) {
        int a = (t >= off) ? sm[t - off] : 0;
        __syncthreads();
        sm[t] += a;
        __syncthreads();
    }
    int excl = sm[t] - v;
    __syncthreads();
    rowptr[(b << 8) + t] = s0 + excl;   // padded rowptr: always safe
    hist[t] = excl;                      // reuse as cursor
    __syncthreads();
    if (inLds) {
        for (int i = t; i < n; i += 256) {
            int2 it = stage[i];
            int r = atomicAdd(&hist[(uint)it.x >> 24], 1);
            csr[s0 + r] = make_int2(it.x & 0xFFFFFF, it.y);
        }
    } else {
        for (int i = t; i < n; i += 256) {
            int2 it = tmp[s0 + i];
            int r = atomicAdd(&hist[(uint)it.x >> 24], 1);
            csr[s0 + r] = make_int2(it.x & 0xFFFFFF, it.y);
        }
    }
}

// ============ gather SpMM (bf16) + residual + LayerNorm ============
// 4 rows per wave, one per 16-lane sub: no cross-sub merge, all-lane epilogue,
// 1 KB contiguous residual/output per wave. One edge per sub per iteration;
// csr 2 ahead, gather 1 ahead. Clamped-out subs gather csr[0]'s row (one hot
// cached line chip-wide; value masked to 0).
template<bool OUT_BF>
__global__ __launch_bounds__(256) void gather_ln_k(
    const uint4* __restrict__ srcU,  // table gathered by user rows
    const uint4* __restrict__ srcI,  // table gathered by item rows
    const uint4* __restrict__ resU, const uint4* __restrict__ resI,
    void* __restrict__ outU, void* __restrict__ outI,
    const int* __restrict__ rowptr, const int2* __restrict__ csr,
    const float* __restrict__ gamma, const float* __restrict__ beta,
    int nu, int N)
{
    int gw = blockIdx.x * 4 + (threadIdx.x >> 6);   // wave id
    if (gw * 4 >= N) return;
    int lane = threadIdx.x & 63;
    int sub  = lane >> 4;   // row slot 0..3
    int l16  = lane & 15;   // 16B chunk in row -> channels l16*8 .. +7

    int row = gw * 4 + sub;
    bool rv = row < N;
    int rowc = rv ? row : N - 1;     // clamped for pointer math only

    int start = rv ? rowptr[row]     : 0;
    int end   = rv ? rowptr[row + 1] : 0;
    int deg   = end - start;
    // wave-max degree (uniform within sub; reduce across the 4 subs)
    int md = deg;
    md = max(md, __shfl_xor(md, 16, 64));
    md = max(md, __shfl_xor(md, 32, 64));

    const uint4* tbl;
    const uint4* res;
    char* outp;
    if (rowc < nu) {
        tbl  = srcU;
        res  = resU + (ll)rowc * 16;
        outp = OUT_BF ? (char*)outU + (ll)rowc * 256
                      : (char*)outU + (ll)rowc * 512;
    } else {
        int k = rowc - nu;
        tbl  = srcI;
        res  = resI + (ll)k * 16;
        outp = OUT_BF ? (char*)outI + (ll)k * 256
                      : (char*)outI + (ll)k * 512;
    }

    f32x2 a01 = {0.f, 0.f}, a23 = {0.f, 0.f}, a45 = {0.f, 0.f}, a67 = {0.f, 0.f};

#define FMA8(q, vv) {                                                   \
        f32x2 b;                                                        \
        b[0] = unpack_lo(q.x); b[1] = unpack_hi(q.x); a01 = vv * b + a01; \
        b[0] = unpack_lo(q.y); b[1] = unpack_hi(q.y); a23 = vv * b + a23; \
        b[0] = unpack_lo(q.z); b[1] = unpack_hi(q.z); a45 = vv * b + a45; \
        b[0] = unpack_lo(q.w); b[1] = unpack_hi(q.w); a67 = vv * b + a67; }

    if (md > 0) {
        // prologue: edge 0 csr+gather in flight, edge 1 csr in flight
        int2 ec0 = csr[(0 < deg) ? start     : 0];
        int2 ec1 = csr[(1 < deg) ? start + 1 : 0];
        uint4 q0 = tbl[(((uint)ec0.x) << 4) + l16];
        for (int k = 0; k < md; ++k) {
            int2 ec2 = csr[((k + 2) < deg) ? (start + k + 2) : 0];
            uint4 q1 = tbl[(((uint)ec1.x) << 4) + l16];
            float vm = (k < deg) ? __int_as_float(ec0.y) : 0.0f;
            f32x2 vv = {vm, vm};
            FMA8(q0, vv);
            ec0 = ec1; ec1 = ec2; q0 = q1;
        }
    }
#undef FMA8

    float a0 = a01[0], a1 = a01[1], a2 = a23[0], a3 = a23[1];
    float a4 = a45[0], a5 = a45[1], a6 = a67[0], a7 = a67[1];

    // residual (bf16 row; 4 consecutive rows -> 1 KB contiguous per wave)
    uint4 r = res[l16];
    a0 += unpack_lo(r.x); a1 += unpack_hi(r.x);
    a2 += unpack_lo(r.y); a3 += unpack_hi(r.y);
    a4 += unpack_lo(r.z); a5 += unpack_hi(r.z);
    a6 += unpack_lo(r.w); a7 += unpack_hi(r.w);

    // LN stats over the 16-lane sub (offsets < 16 stay within the sub)
    float s  = a0+a1+a2+a3+a4+a5+a6+a7;
    float ss = a0*a0+a1*a1+a2*a2+a3*a3+a4*a4+a5*a5+a6*a6+a7*a7;
#pragma unroll
    for (int off = 8; off > 0; off >>= 1) {
        s  += __shfl_xor(s, off, 64);
        ss += __shfl_xor(ss, off, 64);
    }
    float m   = s * (1.0f / 128.0f);
    float var = ss * (1.0f / 128.0f) - m * m;
    float inv = rsqrtf(var + EPS);

    float4 g0 = ((const float4*)gamma)[l16 * 2];
    float4 g1 = ((const float4*)gamma)[l16 * 2 + 1];
    float4 b0 = ((const float4*)beta)[l16 * 2];
    float4 b1 = ((const float4*)beta)[l16 * 2 + 1];
    float o0 = g0.x * (a0 - m) * inv + b0.x;
    float o1 = g0.y * (a1 - m) * inv + b0.y;
    float o2 = g0.z * (a2 - m) * inv + b0.z;
    float o3 = g0.w * (a3 - m) * inv + b0.w;
    float o4 = g1.x * (a4 - m) * inv + b1.x;
    float o5 = g1.y * (a5 - m) * inv + b1.y;
    float o6 = g1.z * (a6 - m) * inv + b1.z;
    float o7 = g1.w * (a7 - m) * inv + b1.w;

    if (rv) {
        if (OUT_BF) {
            uint4 q;
            q.x = pack2(o0, o1); q.y = pack2(o2, o3);
            q.z = pack2(o4, o5); q.w = pack2(o6, o7);
            ((uint4*)outp)[l16] = q;
        } else {
            ((float4*)outp)[l16 * 2]     = make_float4(o0, o1, o2, o3);
            ((float4*)outp)[l16 * 2 + 1] = make_float4(o4, o5, o6, o7);
        }
    }
}

extern "C" void kernel_launch(void* const* d_in, const int* in_sizes, int n_in,
                              void* d_out, int out_size, void* d_ws, size_t ws_size,
                              hipStream_t stream)
{
    const float* user_emb = (const float*)d_in[0];
    const float* item_emb = (const float*)d_in[1];
    const float* vals     = (const float*)d_in[2];
    const float* gamma    = (const float*)d_in[3];
    const float* beta     = (const float*)d_in[4];
    const int*   rows     = (const int*)d_in[5];
    const int*   cols     = (const int*)d_in[6];

    const int nu = in_sizes[0] / 128;   // 100000
    const int ni = in_sizes[1] / 128;   // 200000
    const int ne = in_sizes[2];         // 2000000
    const int N  = nu + ni;
    const int total = 2 * ne;

    float* dout   = (float*)d_out;
    float* dout_u = dout;
    float* dout_i = dout + (ll)nu * 128;

    // bf16 input tables live in d_out until layer 2 overwrites it
    uint* bf_u = (uint*)d_out;                 // nu*64 uints (25.6 MB)
    uint* bf_i = bf_u + (ll)nu * 64;           // ni*64 uints (51.2 MB)

    // ---- geometry ----
    const int NB = (N + 255) >> 8;                       // 1172 coarse bins
    const int hb = (total + CHUNK - 1) / CHUNK;          // 977 chunks (<= NCPAD)

    // ---- workspace layout (~120 MB) ----
    // tmp (32 MB int2) aliases wu/wi (76.8 MB): tmp dies after p3.
    int*  rowptr  = (int*)d_ws;                          // NB*256 ints
    int*  counts  = rowptr + (ll)NB * 256;               // NB*NCPAD (4.8 MB)
    int*  base    = counts + (ll)NB * NCPAD;             // NB*NCPAD (4.8 MB)
    int*  binT    = base + (ll)NB * NCPAD;               // NBMAX
    int*  binptr  = binT + NBMAX;                        // NBMAX (NB+1 used)
    int2* csr     = (int2*)(binptr + NBMAX);             // total int2, 32 MB
    uint* wu_out  = (uint*)(csr + total);                // nu*64, 25.6 MB
    uint* wi_out  = wu_out + (ll)nu * 64;                // ni*64, 51.2 MB
    int2* tmp     = (int2*)wu_out;                       // total int2, 32 MB (aliased)

    const int totT = (nu + ni) * 16;
    const int tb   = (totT + 255) / 256;

    // ---- CSR build: LDS-atomic counting sort ----
    hist_conv_k<<<hb + tb, 256, 0, stream>>>(rows, cols, counts, ne, nu, NB, hb,
                                             user_emb, item_emb,
                                             (uint4*)bf_u, nu * 16, totT);
    s1_kernel<<<NB, 256, 0, stream>>>(counts, base, binT, hb);
    s2_kernel<<<1, 256, 0, stream>>>(binT, binptr, rowptr, NB, N, total);
    p2_kernel<<<hb, 256, 0, stream>>>(rows, cols, vals, base, binptr, tmp, ne, nu, NB);
    p3_kernel<<<NB, 256, 0, stream>>>(tmp, binptr, rowptr, csr);

    const int gblocks = (N + 15) / 16;   // 16 rows per block (4 waves x 4 rows)

    // ---- layer 1 ----
    gather_ln_k<true><<<gblocks, 256, 0, stream>>>(
        (const uint4*)bf_i, (const uint4*)bf_u,
        (const uint4*)bf_u, (const uint4*)bf_i,
        wu_out, wi_out,
        rowptr, csr, gamma, beta, nu, N);

    // ---- layer 2 ----
    gather_ln_k<false><<<gblocks, 256, 0, stream>>>(
        (const uint4*)wi_out, (const uint4*)wu_out,
        (const uint4*)wu_out, (const uint4*)wi_out,
        dout_u, dout_i,
        rowptr, csr, gamma, beta, nu, N);
}